// Round 1
// baseline (1787.240 us; speedup 1.0000x reference)
//
#include <hip/hip_runtime.h>

// Problem constants
#define BSZ   128
#define NTOK  512
#define SDIM  256
#define PDIM  128
#define FDIM  256
#define NIT   30

typedef _Float16 half_t;
typedef _Float16 half8_t __attribute__((ext_vector_type(8)));

// =====================================================================
// K0: transpose W [256,128] -> Wt [128,256]
// =====================================================================
__global__ __launch_bounds__(256) void transpose_w_kernel(const float* __restrict__ W,
                                                          float* __restrict__ Wt) {
    int idx = blockIdx.x * 256 + threadIdx.x;   // [0, 32768)
    int d = idx >> 7;        // 0..255
    int p = idx & 127;       // 0..127
    Wt[p * 256 + d] = W[idx];
}

// =====================================================================
// K1: h = X@W + b -> LayerNorm -> *g+beta -> l2norm.
// X:[65536,256], Wt:[128,256] (col-major of W), out:[65536,128]
// =====================================================================
__global__ __launch_bounds__(256) void proj_kernel(const float* __restrict__ X,
                                                   const float* __restrict__ Wt,
                                                   const float* __restrict__ bias,
                                                   const float* __restrict__ gamma,
                                                   const float* __restrict__ beta,
                                                   float* __restrict__ out) {
    __shared__ float sX[32 * 66];
    __shared__ float sB[128 * 66];
    const int t = threadIdx.x;
    const int row0 = blockIdx.x * 32;
    const int cg = t & 31;      // col group
    const int rg = t >> 5;      // 0..7
    float acc[4][4] = {};

    for (int dc = 0; dc < 4; ++dc) {   // 4 k-chunks of 64
#pragma unroll
        for (int i = 0; i < 2; ++i) {  // stage 32x64 X chunk
            int e = t + 256 * i;
            int r = e >> 4, k4 = (e & 15) * 4;
            float4 v = *(const float4*)&X[(size_t)(row0 + r) * 256 + dc * 64 + k4];
            float* dst = &sX[r * 66 + k4];
            dst[0] = v.x; dst[1] = v.y; dst[2] = v.z; dst[3] = v.w;
        }
#pragma unroll
        for (int i = 0; i < 8; ++i) {  // stage 128x64 W chunk
            int e = t + 256 * i;
            int c = e >> 4, k4 = (e & 15) * 4;
            float4 v = *(const float4*)&Wt[(size_t)c * 256 + dc * 64 + k4];
            float* dst = &sB[c * 66 + k4];
            dst[0] = v.x; dst[1] = v.y; dst[2] = v.z; dst[3] = v.w;
        }
        __syncthreads();
#pragma unroll 8
        for (int kk = 0; kk < 64; kk += 2) {
            float2 a2[4], b2[4];
#pragma unroll
            for (int j = 0; j < 4; ++j) b2[j] = *(const float2*)&sB[(cg + 32 * j) * 66 + kk];
#pragma unroll
            for (int i = 0; i < 4; ++i) a2[i] = *(const float2*)&sX[(rg + 8 * i) * 66 + kk];
#pragma unroll
            for (int i = 0; i < 4; ++i)
#pragma unroll
                for (int j = 0; j < 4; ++j)
                    acc[i][j] += a2[i].x * b2[j].x + a2[i].y * b2[j].y;
        }
        __syncthreads();
    }

    float bia[4], gam[4], bet[4];
#pragma unroll
    for (int j = 0; j < 4; ++j) {
        int c = cg + 32 * j;
        bia[j] = bias[c]; gam[j] = gamma[c]; bet[j] = beta[c];
    }

#pragma unroll
    for (int i = 0; i < 4; ++i) {
        int r = rg + 8 * i;
        float h[4];
        float s1 = 0.f, s2 = 0.f;
#pragma unroll
        for (int j = 0; j < 4; ++j) {
            h[j] = acc[i][j] + bia[j];
            s1 += h[j];
            s2 += h[j] * h[j];
        }
        for (int m = 1; m < 32; m <<= 1) {
            s1 += __shfl_xor(s1, m);
            s2 += __shfl_xor(s2, m);
        }
        float mu  = s1 * (1.f / 128.f);
        float var = s2 * (1.f / 128.f) - mu * mu;
        float rstd = 1.f / sqrtf(var + 1e-5f);
        float y[4]; float s3 = 0.f;
#pragma unroll
        for (int j = 0; j < 4; ++j) {
            y[j] = (h[j] - mu) * rstd * gam[j] + bet[j];
            s3 += y[j] * y[j];
        }
        for (int m = 1; m < 32; m <<= 1) s3 += __shfl_xor(s3, m);
        float inv = 1.f / fmaxf(sqrtf(s3), 1e-12f);
#pragma unroll
        for (int j = 0; j < 4; ++j)
            out[(size_t)(row0 + r) * 128 + cg + 32 * j] = y[j] * inv;
    }
}

// =====================================================================
// K2: K[b,n,m] = exp(-clip(1 - Sp[b,n].Fp[b,m],0,2)/0.1)
//   -> fp32 into d_out P region (read by final_kernel)
//   -> fp16 into d_out FT region (read by sinkhorn passes)
// =====================================================================
__global__ __launch_bounds__(256) void cosk_kernel(const float* __restrict__ SP,
                                                   const float* __restrict__ FP,
                                                   float* __restrict__ Kout,
                                                   half_t* __restrict__ K16out) {
    const int b = blockIdx.y;
    const int tile = blockIdx.x;
    const int n0 = (tile >> 3) * 64, m0 = (tile & 7) * 64;
    __shared__ float sA[64 * 66];
    __shared__ float sB[64 * 66];
    const float* A  = SP + (size_t)b * NTOK * PDIM;
    const float* Bm = FP + (size_t)b * NTOK * PDIM;
    const int t = threadIdx.x;
    const int mg = t & 15, ng = t >> 4;
    float acc[4][4] = {};

    for (int kc = 0; kc < 2; ++kc) {   // 2 k-chunks of 64 (PDIM=128)
#pragma unroll
        for (int i = 0; i < 4; ++i) {
            int e = t + 256 * i;           // 0..1023
            int r = e >> 4, k4 = (e & 15) * 4;
            float4 va = *(const float4*)&A [(size_t)(n0 + r) * 128 + kc * 64 + k4];
            float4 vb = *(const float4*)&Bm[(size_t)(m0 + r) * 128 + kc * 64 + k4];
            float* da = &sA[r * 66 + k4];
            da[0] = va.x; da[1] = va.y; da[2] = va.z; da[3] = va.w;
            float* db = &sB[r * 66 + k4];
            db[0] = vb.x; db[1] = vb.y; db[2] = vb.z; db[3] = vb.w;
        }
        __syncthreads();
#pragma unroll 8
        for (int kk = 0; kk < 64; kk += 2) {
            float2 a2[4], b2[4];
#pragma unroll
            for (int i = 0; i < 4; ++i) a2[i] = *(const float2*)&sA[(ng + 16 * i) * 66 + kk];
#pragma unroll
            for (int j = 0; j < 4; ++j) b2[j] = *(const float2*)&sB[(mg + 16 * j) * 66 + kk];
#pragma unroll
            for (int i = 0; i < 4; ++i)
#pragma unroll
                for (int j = 0; j < 4; ++j)
                    acc[i][j] += a2[i].x * b2[j].x + a2[i].y * b2[j].y;
        }
        __syncthreads();
    }

#pragma unroll
    for (int i = 0; i < 4; ++i) {
        int n = n0 + ng + 16 * i;
#pragma unroll
        for (int j = 0; j < 4; ++j) {
            int m = m0 + mg + 16 * j;
            float C = fminf(fmaxf(1.f - acc[i][j], 0.f), 2.f);
            float K = expf(-10.f * C);
            size_t gidx = ((size_t)b * NTOK + n) * NTOK + m;
            Kout[gidx] = K;
            K16out[gidx] = (half_t)K;
        }
    }
}

// =====================================================================
// K3 (fused Sinkhorn iteration): block = (b, 64-row strip s).
// Memory-level-parallelism version: ALL 16 row-loads of a wave's strip
// are hoisted into registers up front (16 KB in flight per wave), then
// the 16 row-dots, the 16 independent 6-step xor-butterflies, and the
// colacc pass run from register-resident K.  Math order per row matches
// the previous version up to fp32 associativity (tree dot).
// =====================================================================
__global__ __launch_bounds__(256, 4) void sinkhorn_iter_kernel(const half_t* __restrict__ K16,
                                                               float* __restrict__ parts,
                                                               float* __restrict__ U,
                                                               int iter) {
    const int blk = blockIdx.x;
    const int b = blk >> 3, s = blk & 7;
    __shared__ float vs[NTOK];
    __shared__ float wacc[4][NTOK];
    const int t = threadIdx.x;
    const int wave = t >> 6, lane = t & 63;

    if (iter == 0) {
        vs[t] = 1.f; vs[t + 256] = 1.f;
    } else {
        for (int m = t; m < NTOK; m += 256) {
            float sum = 0.f;
            const float* pp = parts + (size_t)b * 8 * NTOK + m;
#pragma unroll
            for (int q = 0; q < 8; ++q) sum += pp[q * NTOK];
            float v = (1.f / 512.f) / (sum + 1e-8f);
            vs[m] = fminf(fmaxf(v, 1e-8f), 1e8f);
        }
    }
    __syncthreads();

    float vl[8];
#pragma unroll
    for (int j = 0; j < 8; ++j) vl[j] = vs[lane * 8 + j];

    const half_t* Kbase = K16 + ((size_t)b * NTOK + s * 64 + wave * 16) * NTOK + lane * 8;

    // Hoist all 16 row loads: 16 x global_load_dwordx4 in flight per wave.
    half8_t kb[16];
#pragma unroll
    for (int rr = 0; rr < 16; ++rr)
        kb[rr] = *(const half8_t*)(Kbase + (size_t)rr * NTOK);

    float colacc[8] = {};
    float ureg = 0.f;

#pragma unroll
    for (int h = 0; h < 2; ++h) {
        // per-lane partial dots for 8 rows (independent)
        float p[8];
#pragma unroll
        for (int rr = 0; rr < 8; ++rr) {
            const half8_t kk = kb[h * 8 + rr];
            float d0 = (float)kk[0] * vl[0] + (float)kk[1] * vl[1];
            float d1 = (float)kk[2] * vl[2] + (float)kk[3] * vl[3];
            float d2 = (float)kk[4] * vl[4] + (float)kk[5] * vl[5];
            float d3 = (float)kk[6] * vl[6] + (float)kk[7] * vl[7];
            p[rr] = (d0 + d1) + (d2 + d3);
        }
        // 8 independent butterfly chains -> DS latency hidden by ILP
#pragma unroll
        for (int m = 1; m < 64; m <<= 1)
#pragma unroll
            for (int rr = 0; rr < 8; ++rr)
                p[rr] += __shfl_xor(p[rr], m);
#pragma unroll
        for (int rr = 0; rr < 8; ++rr) {
            float u_r = (1.f / 512.f) / (p[rr] + 1e-8f);
            if (lane == h * 8 + rr) ureg = u_r;   // cndmask, no divergence cost
#pragma unroll
            for (int j = 0; j < 8; ++j)
                colacc[j] += (float)kb[h * 8 + rr][j] * u_r;
        }
    }
    if (lane < 16) U[(size_t)b * NTOK + s * 64 + wave * 16 + lane] = ureg;

    *(float4*)&wacc[wave][lane * 8]     = *(float4*)&colacc[0];
    *(float4*)&wacc[wave][lane * 8 + 4] = *(float4*)&colacc[4];
    __syncthreads();
    for (int m = t; m < NTOK; m += 256) {
        parts[((size_t)(b * 8 + s)) * NTOK + m] =
            wacc[0][m] + wacc[1][m] + wacc[2][m] + wacc[3][m];
    }
}

// =====================================================================
// K5: final.  Software-pipelined: K-chunk loads for mc+1 are issued
// before the GEMM on chunk mc (HBM latency hidden under FMAs), P is
// computed/stored after the GEMM into the other LDS buffer (double-
// buffered sP, one barrier per chunk).  GEMM phase reads sP as float4
// (ds_read_b128) -> 4x fewer LDS instructions.
// NOTE: FT writes land exactly on this strip's K16 bytes (FT region) --
// K16 is dead after the sinkhorn loop, and final reads only K32.
// =====================================================================
__global__ __launch_bounds__(256, 4) void final_kernel(const float* __restrict__ parts,
                                                       const float* __restrict__ u,
                                                       const float* __restrict__ F,
                                                       float* __restrict__ Pout,
                                                       float* __restrict__ FTout) {
    const int blk = blockIdx.x;
    const int b = blk >> 3, s = blk & 7;
    __shared__ float vs[NTOK];
    __shared__ float us[64];
    __shared__ float sP[2][64 * 68];
    const int t = threadIdx.x;

    for (int m = t; m < NTOK; m += 256) {
        float sum = 0.f;
        const float* pp = parts + (size_t)b * 8 * NTOK + m;
#pragma unroll
        for (int q = 0; q < 8; ++q) sum += pp[q * NTOK];
        float v = (1.f / 512.f) / (sum + 1e-8f);
        vs[m] = fminf(fmaxf(v, 1e-8f), 1e8f);
    }
    if (t < 64) {
        float uu = u[(size_t)b * NTOK + s * 64 + t];
        us[t] = fminf(fmaxf(uu, 1e-8f), 1e8f);
    }

    const int dg = t & 63;   // F cols 4*dg..+4
    const int ng = t >> 6;   // row group: rows 16*ng..+16
    const float* Fb = F + (size_t)b * NTOK * FDIM;
    float* Pbase = Pout + ((size_t)b * NTOK + s * 64) * NTOK;

    float4 kreg[4];
    auto issue_load = [&](int mc) {
#pragma unroll
        for (int i = 0; i < 4; ++i) {
            int e = t + 256 * i;            // 0..1023 float4 slots
            int r = e >> 4, m4 = (e & 15) * 4;
            kreg[i] = *(const float4*)&Pbase[(size_t)r * NTOK + mc * 64 + m4];
        }
    };
    auto emit = [&](int mc, int buf) {      // P = u*K*v -> global (in place) + LDS
#pragma unroll
        for (int i = 0; i < 4; ++i) {
            int e = t + 256 * i;
            int r = e >> 4, m4 = (e & 15) * 4;
            float ur = us[r];
            float4 p4;
            p4.x = kreg[i].x * ur * vs[mc * 64 + m4 + 0];
            p4.y = kreg[i].y * ur * vs[mc * 64 + m4 + 1];
            p4.z = kreg[i].z * ur * vs[mc * 64 + m4 + 2];
            p4.w = kreg[i].w * ur * vs[mc * 64 + m4 + 3];
            *(float4*)&Pbase[(size_t)r * NTOK + mc * 64 + m4] = p4;
            float* dst = &sP[buf][r * 68 + m4];
            dst[0] = p4.x; dst[1] = p4.y; dst[2] = p4.z; dst[3] = p4.w;
        }
    };

    float acc[16][4] = {};

    issue_load(0);
    __syncthreads();          // vs/us visible
    emit(0, 0);
    __syncthreads();
    int cur = 0;

    for (int mc = 0; mc < 8; ++mc) {
        if (mc < 7) issue_load(mc + 1);     // next chunk's K in flight during GEMM

        // FT[64,256] += P_chunk[64,64] @ F[mchunk,256], float4 LDS reads
        const float* Fc = Fb + (size_t)(mc * 64) * FDIM + 4 * dg;
        const float* sp = sP[cur];
        for (int mm = 0; mm < 64; mm += 4) {
            float4 f0 = *(const float4*)&Fc[(size_t)(mm + 0) * FDIM];
            float4 f1 = *(const float4*)&Fc[(size_t)(mm + 1) * FDIM];
            float4 f2 = *(const float4*)&Fc[(size_t)(mm + 2) * FDIM];
            float4 f3 = *(const float4*)&Fc[(size_t)(mm + 3) * FDIM];
#pragma unroll
            for (int i = 0; i < 16; ++i) {
                float4 p = *(const float4*)&sp[(ng * 16 + i) * 68 + mm];
                acc[i][0] += p.x * f0.x + p.y * f1.x + p.z * f2.x + p.w * f3.x;
                acc[i][1] += p.x * f0.y + p.y * f1.y + p.z * f2.y + p.w * f3.y;
                acc[i][2] += p.x * f0.z + p.y * f1.z + p.z * f2.z + p.w * f3.z;
                acc[i][3] += p.x * f0.w + p.y * f1.w + p.z * f2.w + p.w * f3.w;
            }
        }

        if (mc < 7) {
            emit(mc + 1, cur ^ 1);
            __syncthreads();
            cur ^= 1;
        }
    }

#pragma unroll
    for (int i = 0; i < 16; ++i) {
        float4 o;
        o.x = acc[i][0]; o.y = acc[i][1]; o.z = acc[i][2]; o.w = acc[i][3];
        *(float4*)&FTout[((size_t)b * NTOK + s * 64 + ng * 16 + i) * FDIM + 4 * dg] = o;
    }
}

// =====================================================================
extern "C" void kernel_launch(void* const* d_in, const int* in_sizes, int n_in,
                              void* d_out, int out_size, void* d_ws, size_t ws_size,
                              hipStream_t stream) {
    const float* S      = (const float*)d_in[0];
    const float* F      = (const float*)d_in[1];
    const float* W_s    = (const float*)d_in[2];
    const float* b_s    = (const float*)d_in[3];
    const float* g_s    = (const float*)d_in[4];
    const float* beta_s = (const float*)d_in[5];
    const float* W_f    = (const float*)d_in[6];
    const float* b_f    = (const float*)d_in[7];
    const float* g_f    = (const float*)d_in[8];
    const float* beta_f = (const float*)d_in[9];

    float* wsf  = (float*)d_ws;
    float* WT_s = wsf;                       // 32768
    float* WT_f = wsf + 32768;               // 32768
    float* SP   = wsf + 65536;               // 65536*128
    float* FP   = SP + (size_t)65536 * 128;  // 65536*128
    float* U    = FP + (size_t)65536 * 128;  // 65536
    float* PARTS = U + 65536;                // 128*8*512

    float* Pout = (float*)d_out;                      // [128,512,512] (K32 then P, in place)
    float* FT   = Pout + (size_t)BSZ * NTOK * NTOK;   // [128,512,256]
    // fp16 K lives in the FT region during the sinkhorn phase:
    // 128*512*512*2 bytes == 128*512*256*4 bytes exactly.
    half_t* K16 = (half_t*)FT;

    transpose_w_kernel<<<128, 256, 0, stream>>>(W_s, WT_s);
    transpose_w_kernel<<<128, 256, 0, stream>>>(W_f, WT_f);

    proj_kernel<<<2048, 256, 0, stream>>>(S, WT_s, b_s, g_s, beta_s, SP);
    proj_kernel<<<2048, 256, 0, stream>>>(F, WT_f, b_f, g_f, beta_f, FP);

    cosk_kernel<<<dim3(64, 128), 256, 0, stream>>>(SP, FP, Pout, K16);

    for (int it = 0; it < NIT; ++it) {
        sinkhorn_iter_kernel<<<1024, 256, 0, stream>>>(K16, PARTS, U, it);
    }

    final_kernel<<<1024, 256, 0, stream>>>(PARTS, U, F, Pout, FT);
}

// Round 2
// 1462.554 us; speedup vs baseline: 1.2220x; 1.2220x over previous
//
#include <hip/hip_runtime.h>

// Problem constants
#define BSZ   128
#define NTOK  512
#define SDIM  256
#define PDIM  128
#define FDIM  256
#define NIT   30

typedef _Float16 half_t;
typedef _Float16 half8_t __attribute__((ext_vector_type(8)));

// =====================================================================
// K0: transpose W [256,128] -> Wt [128,256]
// =====================================================================
__global__ __launch_bounds__(256) void transpose_w_kernel(const float* __restrict__ W,
                                                          float* __restrict__ Wt) {
    int idx = blockIdx.x * 256 + threadIdx.x;   // [0, 32768)
    int d = idx >> 7;        // 0..255
    int p = idx & 127;       // 0..127
    Wt[p * 256 + d] = W[idx];
}

// =====================================================================
// K1: h = X@W + b -> LayerNorm -> *g+beta -> l2norm.
// X:[65536,256], Wt:[128,256] (col-major of W), out:[65536,128]
// =====================================================================
__global__ __launch_bounds__(256) void proj_kernel(const float* __restrict__ X,
                                                   const float* __restrict__ Wt,
                                                   const float* __restrict__ bias,
                                                   const float* __restrict__ gamma,
                                                   const float* __restrict__ beta,
                                                   float* __restrict__ out) {
    __shared__ float sX[32 * 66];
    __shared__ float sB[128 * 66];
    const int t = threadIdx.x;
    const int row0 = blockIdx.x * 32;
    const int cg = t & 31;      // col group
    const int rg = t >> 5;      // 0..7
    float acc[4][4] = {};

    for (int dc = 0; dc < 4; ++dc) {   // 4 k-chunks of 64
#pragma unroll
        for (int i = 0; i < 2; ++i) {  // stage 32x64 X chunk
            int e = t + 256 * i;
            int r = e >> 4, k4 = (e & 15) * 4;
            float4 v = *(const float4*)&X[(size_t)(row0 + r) * 256 + dc * 64 + k4];
            float* dst = &sX[r * 66 + k4];
            dst[0] = v.x; dst[1] = v.y; dst[2] = v.z; dst[3] = v.w;
        }
#pragma unroll
        for (int i = 0; i < 8; ++i) {  // stage 128x64 W chunk
            int e = t + 256 * i;
            int c = e >> 4, k4 = (e & 15) * 4;
            float4 v = *(const float4*)&Wt[(size_t)c * 256 + dc * 64 + k4];
            float* dst = &sB[c * 66 + k4];
            dst[0] = v.x; dst[1] = v.y; dst[2] = v.z; dst[3] = v.w;
        }
        __syncthreads();
#pragma unroll 8
        for (int kk = 0; kk < 64; kk += 2) {
            float2 a2[4], b2[4];
#pragma unroll
            for (int j = 0; j < 4; ++j) b2[j] = *(const float2*)&sB[(cg + 32 * j) * 66 + kk];
#pragma unroll
            for (int i = 0; i < 4; ++i) a2[i] = *(const float2*)&sX[(rg + 8 * i) * 66 + kk];
#pragma unroll
            for (int i = 0; i < 4; ++i)
#pragma unroll
                for (int j = 0; j < 4; ++j)
                    acc[i][j] += a2[i].x * b2[j].x + a2[i].y * b2[j].y;
        }
        __syncthreads();
    }

    float bia[4], gam[4], bet[4];
#pragma unroll
    for (int j = 0; j < 4; ++j) {
        int c = cg + 32 * j;
        bia[j] = bias[c]; gam[j] = gamma[c]; bet[j] = beta[c];
    }

#pragma unroll
    for (int i = 0; i < 4; ++i) {
        int r = rg + 8 * i;
        float h[4];
        float s1 = 0.f, s2 = 0.f;
#pragma unroll
        for (int j = 0; j < 4; ++j) {
            h[j] = acc[i][j] + bia[j];
            s1 += h[j];
            s2 += h[j] * h[j];
        }
        for (int m = 1; m < 32; m <<= 1) {
            s1 += __shfl_xor(s1, m);
            s2 += __shfl_xor(s2, m);
        }
        float mu  = s1 * (1.f / 128.f);
        float var = s2 * (1.f / 128.f) - mu * mu;
        float rstd = 1.f / sqrtf(var + 1e-5f);
        float y[4]; float s3 = 0.f;
#pragma unroll
        for (int j = 0; j < 4; ++j) {
            y[j] = (h[j] - mu) * rstd * gam[j] + bet[j];
            s3 += y[j] * y[j];
        }
        for (int m = 1; m < 32; m <<= 1) s3 += __shfl_xor(s3, m);
        float inv = 1.f / fmaxf(sqrtf(s3), 1e-12f);
#pragma unroll
        for (int j = 0; j < 4; ++j)
            out[(size_t)(row0 + r) * 128 + cg + 32 * j] = y[j] * inv;
    }
}

// =====================================================================
// K2: K[b,n,m] = exp(-clip(1 - Sp[b,n].Fp[b,m],0,2)/0.1)
//   -> fp32 into d_out P region (read by final_kernel)
//   -> fp16 into d_out FT region (read by sinkhorn passes)
// =====================================================================
__global__ __launch_bounds__(256) void cosk_kernel(const float* __restrict__ SP,
                                                   const float* __restrict__ FP,
                                                   float* __restrict__ Kout,
                                                   half_t* __restrict__ K16out) {
    const int b = blockIdx.y;
    const int tile = blockIdx.x;
    const int n0 = (tile >> 3) * 64, m0 = (tile & 7) * 64;
    __shared__ float sA[64 * 66];
    __shared__ float sB[64 * 66];
    const float* A  = SP + (size_t)b * NTOK * PDIM;
    const float* Bm = FP + (size_t)b * NTOK * PDIM;
    const int t = threadIdx.x;
    const int mg = t & 15, ng = t >> 4;
    float acc[4][4] = {};

    for (int kc = 0; kc < 2; ++kc) {   // 2 k-chunks of 64 (PDIM=128)
#pragma unroll
        for (int i = 0; i < 4; ++i) {
            int e = t + 256 * i;           // 0..1023
            int r = e >> 4, k4 = (e & 15) * 4;
            float4 va = *(const float4*)&A [(size_t)(n0 + r) * 128 + kc * 64 + k4];
            float4 vb = *(const float4*)&Bm[(size_t)(m0 + r) * 128 + kc * 64 + k4];
            float* da = &sA[r * 66 + k4];
            da[0] = va.x; da[1] = va.y; da[2] = va.z; da[3] = va.w;
            float* db = &sB[r * 66 + k4];
            db[0] = vb.x; db[1] = vb.y; db[2] = vb.z; db[3] = vb.w;
        }
        __syncthreads();
#pragma unroll 8
        for (int kk = 0; kk < 64; kk += 2) {
            float2 a2[4], b2[4];
#pragma unroll
            for (int i = 0; i < 4; ++i) a2[i] = *(const float2*)&sA[(ng + 16 * i) * 66 + kk];
#pragma unroll
            for (int j = 0; j < 4; ++j) b2[j] = *(const float2*)&sB[(mg + 16 * j) * 66 + kk];
#pragma unroll
            for (int i = 0; i < 4; ++i)
#pragma unroll
                for (int j = 0; j < 4; ++j)
                    acc[i][j] += a2[i].x * b2[j].x + a2[i].y * b2[j].y;
        }
        __syncthreads();
    }

#pragma unroll
    for (int i = 0; i < 4; ++i) {
        int n = n0 + ng + 16 * i;
#pragma unroll
        for (int j = 0; j < 4; ++j) {
            int m = m0 + mg + 16 * j;
            float C = fminf(fmaxf(1.f - acc[i][j], 0.f), 2.f);
            float K = expf(-10.f * C);
            size_t gidx = ((size_t)b * NTOK + n) * NTOK + m;
            Kout[gidx] = K;
            K16out[gidx] = (half_t)K;
        }
    }
}

// =====================================================================
// K3 (fused Sinkhorn iteration): block = (b, 64-row strip s).
// Pipelined, register-budgeted: rows processed in groups of 4 with a
// depth-2 lookahead (rolling 3-slot buffer, fully unrolled so every
// buffer index is compile-time constant -> stays in VGPRs, no scratch).
// Steady state: 8 row-loads (8 KB) in flight per wave.  Peak VGPR ~95
// (48 buf + 8 colacc + 8 vl + temps) -- no launch_bounds cap, no spill.
// =====================================================================
__global__ __launch_bounds__(256) void sinkhorn_iter_kernel(const half_t* __restrict__ K16,
                                                            float* __restrict__ parts,
                                                            float* __restrict__ U,
                                                            int iter) {
    const int blk = blockIdx.x;
    const int b = blk >> 3, s = blk & 7;
    __shared__ float vs[NTOK];
    __shared__ float wacc[4][NTOK];
    const int t = threadIdx.x;
    const int wave = t >> 6, lane = t & 63;

    if (iter == 0) {
        vs[t] = 1.f; vs[t + 256] = 1.f;
    } else {
        for (int m = t; m < NTOK; m += 256) {
            float sum = 0.f;
            const float* pp = parts + (size_t)b * 8 * NTOK + m;
#pragma unroll
            for (int q = 0; q < 8; ++q) sum += pp[q * NTOK];
            float v = (1.f / 512.f) / (sum + 1e-8f);
            vs[m] = fminf(fmaxf(v, 1e-8f), 1e8f);
        }
    }
    __syncthreads();

    float vl[8];
#pragma unroll
    for (int j = 0; j < 8; ++j) vl[j] = vs[lane * 8 + j];

    const half_t* Kbase = K16 + ((size_t)b * NTOK + s * 64 + wave * 16) * NTOK + lane * 8;

    // prologue: groups 0 and 1 in flight (8 loads / 8 KB per wave)
    half8_t buf[3][4];
#pragma unroll
    for (int r = 0; r < 4; ++r) buf[0][r] = *(const half8_t*)(Kbase + (size_t)r * NTOK);
#pragma unroll
    for (int r = 0; r < 4; ++r) buf[1][r] = *(const half8_t*)(Kbase + (size_t)(4 + r) * NTOK);

    float colacc[8] = {};
    float ureg = 0.f;

#pragma unroll
    for (int g = 0; g < 4; ++g) {
        if (g < 2) {     // issue group g+2 while processing group g
#pragma unroll
            for (int r = 0; r < 4; ++r)
                buf[(g + 2) % 3][r] = *(const half8_t*)(Kbase + (size_t)((g + 2) * 4 + r) * NTOK);
        }
        // per-lane partial dots for the 4 rows of this group
        float p[4];
#pragma unroll
        for (int rr = 0; rr < 4; ++rr) {
            const half8_t kk = buf[g % 3][rr];
            float d0 = (float)kk[0] * vl[0] + (float)kk[1] * vl[1];
            float d1 = (float)kk[2] * vl[2] + (float)kk[3] * vl[3];
            float d2 = (float)kk[4] * vl[4] + (float)kk[5] * vl[5];
            float d3 = (float)kk[6] * vl[6] + (float)kk[7] * vl[7];
            p[rr] = (d0 + d1) + (d2 + d3);
        }
        // 4 independent butterfly chains -> DS latency hidden by ILP
#pragma unroll
        for (int m = 1; m < 64; m <<= 1)
#pragma unroll
            for (int rr = 0; rr < 4; ++rr)
                p[rr] += __shfl_xor(p[rr], m);
#pragma unroll
        for (int rr = 0; rr < 4; ++rr) {
            float u_r = (1.f / 512.f) / (p[rr] + 1e-8f);
            if (lane == g * 4 + rr) ureg = u_r;   // cndmask, no divergence cost
#pragma unroll
            for (int j = 0; j < 8; ++j)
                colacc[j] += (float)buf[g % 3][rr][j] * u_r;
        }
    }
    if (lane < 16) U[(size_t)b * NTOK + s * 64 + wave * 16 + lane] = ureg;

    *(float4*)&wacc[wave][lane * 8]     = *(float4*)&colacc[0];
    *(float4*)&wacc[wave][lane * 8 + 4] = *(float4*)&colacc[4];
    __syncthreads();
    for (int m = t; m < NTOK; m += 256) {
        parts[((size_t)(b * 8 + s)) * NTOK + m] =
            wacc[0][m] + wacc[1][m] + wacc[2][m] + wacc[3][m];
    }
}

// =====================================================================
// K5: final.  Software-pipelined: K-chunk loads for mc+1 are issued
// before the GEMM on chunk mc (HBM latency hidden under FMAs), P is
// computed/stored after the GEMM into the other LDS buffer (double-
// buffered sP, one barrier per chunk).  GEMM phase reads sP as float4
// (ds_read_b128) -> 4x fewer LDS instructions.
// NOTE: FT writes land exactly on this strip's K16 bytes (FT region) --
// K16 is dead after the sinkhorn loop, and final reads only K32.
// =====================================================================
__global__ __launch_bounds__(256, 4) void final_kernel(const float* __restrict__ parts,
                                                       const float* __restrict__ u,
                                                       const float* __restrict__ F,
                                                       float* __restrict__ Pout,
                                                       float* __restrict__ FTout) {
    const int blk = blockIdx.x;
    const int b = blk >> 3, s = blk & 7;
    __shared__ float vs[NTOK];
    __shared__ float us[64];
    __shared__ float sP[2][64 * 68];
    const int t = threadIdx.x;

    for (int m = t; m < NTOK; m += 256) {
        float sum = 0.f;
        const float* pp = parts + (size_t)b * 8 * NTOK + m;
#pragma unroll
        for (int q = 0; q < 8; ++q) sum += pp[q * NTOK];
        float v = (1.f / 512.f) / (sum + 1e-8f);
        vs[m] = fminf(fmaxf(v, 1e-8f), 1e8f);
    }
    if (t < 64) {
        float uu = u[(size_t)b * NTOK + s * 64 + t];
        us[t] = fminf(fmaxf(uu, 1e-8f), 1e8f);
    }

    const int dg = t & 63;   // F cols 4*dg..+4
    const int ng = t >> 6;   // row group: rows 16*ng..+16
    const float* Fb = F + (size_t)b * NTOK * FDIM;
    float* Pbase = Pout + ((size_t)b * NTOK + s * 64) * NTOK;

    float4 kreg[4];
    auto issue_load = [&](int mc) {
#pragma unroll
        for (int i = 0; i < 4; ++i) {
            int e = t + 256 * i;            // 0..1023 float4 slots
            int r = e >> 4, m4 = (e & 15) * 4;
            kreg[i] = *(const float4*)&Pbase[(size_t)r * NTOK + mc * 64 + m4];
        }
    };
    auto emit = [&](int mc, int buf) {      // P = u*K*v -> global (in place) + LDS
#pragma unroll
        for (int i = 0; i < 4; ++i) {
            int e = t + 256 * i;
            int r = e >> 4, m4 = (e & 15) * 4;
            float ur = us[r];
            float4 p4;
            p4.x = kreg[i].x * ur * vs[mc * 64 + m4 + 0];
            p4.y = kreg[i].y * ur * vs[mc * 64 + m4 + 1];
            p4.z = kreg[i].z * ur * vs[mc * 64 + m4 + 2];
            p4.w = kreg[i].w * ur * vs[mc * 64 + m4 + 3];
            *(float4*)&Pbase[(size_t)r * NTOK + mc * 64 + m4] = p4;
            float* dst = &sP[buf][r * 68 + m4];
            dst[0] = p4.x; dst[1] = p4.y; dst[2] = p4.z; dst[3] = p4.w;
        }
    };

    float acc[16][4] = {};

    issue_load(0);
    __syncthreads();          // vs/us visible
    emit(0, 0);
    __syncthreads();
    int cur = 0;

    for (int mc = 0; mc < 8; ++mc) {
        if (mc < 7) issue_load(mc + 1);     // next chunk's K in flight during GEMM

        // FT[64,256] += P_chunk[64,64] @ F[mchunk,256], float4 LDS reads
        const float* Fc = Fb + (size_t)(mc * 64) * FDIM + 4 * dg;
        const float* sp = sP[cur];
        for (int mm = 0; mm < 64; mm += 4) {
            float4 f0 = *(const float4*)&Fc[(size_t)(mm + 0) * FDIM];
            float4 f1 = *(const float4*)&Fc[(size_t)(mm + 1) * FDIM];
            float4 f2 = *(const float4*)&Fc[(size_t)(mm + 2) * FDIM];
            float4 f3 = *(const float4*)&Fc[(size_t)(mm + 3) * FDIM];
#pragma unroll
            for (int i = 0; i < 16; ++i) {
                float4 p = *(const float4*)&sp[(ng * 16 + i) * 68 + mm];
                acc[i][0] += p.x * f0.x + p.y * f1.x + p.z * f2.x + p.w * f3.x;
                acc[i][1] += p.x * f0.y + p.y * f1.y + p.z * f2.y + p.w * f3.y;
                acc[i][2] += p.x * f0.z + p.y * f1.z + p.z * f2.z + p.w * f3.z;
                acc[i][3] += p.x * f0.w + p.y * f1.w + p.z * f2.w + p.w * f3.w;
            }
        }

        if (mc < 7) {
            emit(mc + 1, cur ^ 1);
            __syncthreads();
            cur ^= 1;
        }
    }

#pragma unroll
    for (int i = 0; i < 16; ++i) {
        float4 o;
        o.x = acc[i][0]; o.y = acc[i][1]; o.z = acc[i][2]; o.w = acc[i][3];
        *(float4*)&FTout[((size_t)b * NTOK + s * 64 + ng * 16 + i) * FDIM + 4 * dg] = o;
    }
}

// =====================================================================
extern "C" void kernel_launch(void* const* d_in, const int* in_sizes, int n_in,
                              void* d_out, int out_size, void* d_ws, size_t ws_size,
                              hipStream_t stream) {
    const float* S      = (const float*)d_in[0];
    const float* F      = (const float*)d_in[1];
    const float* W_s    = (const float*)d_in[2];
    const float* b_s    = (const float*)d_in[3];
    const float* g_s    = (const float*)d_in[4];
    const float* beta_s = (const float*)d_in[5];
    const float* W_f    = (const float*)d_in[6];
    const float* b_f    = (const float*)d_in[7];
    const float* g_f    = (const float*)d_in[8];
    const float* beta_f = (const float*)d_in[9];

    float* wsf  = (float*)d_ws;
    float* WT_s = wsf;                       // 32768
    float* WT_f = wsf + 32768;               // 32768
    float* SP   = wsf + 65536;               // 65536*128
    float* FP   = SP + (size_t)65536 * 128;  // 65536*128
    float* U    = FP + (size_t)65536 * 128;  // 65536
    float* PARTS = U + 65536;                // 128*8*512

    float* Pout = (float*)d_out;                      // [128,512,512] (K32 then P, in place)
    float* FT   = Pout + (size_t)BSZ * NTOK * NTOK;   // [128,512,256]
    // fp16 K lives in the FT region during the sinkhorn phase:
    // 128*512*512*2 bytes == 128*512*256*4 bytes exactly.
    half_t* K16 = (half_t*)FT;

    transpose_w_kernel<<<128, 256, 0, stream>>>(W_s, WT_s);
    transpose_w_kernel<<<128, 256, 0, stream>>>(W_f, WT_f);

    proj_kernel<<<2048, 256, 0, stream>>>(S, WT_s, b_s, g_s, beta_s, SP);
    proj_kernel<<<2048, 256, 0, stream>>>(F, WT_f, b_f, g_f, beta_f, FP);

    cosk_kernel<<<dim3(64, 128), 256, 0, stream>>>(SP, FP, Pout, K16);

    for (int it = 0; it < NIT; ++it) {
        sinkhorn_iter_kernel<<<1024, 256, 0, stream>>>(K16, PARTS, U, it);
    }

    final_kernel<<<1024, 256, 0, stream>>>(PARTS, U, F, Pout, FT);
}